// Round 7
// baseline (790.036 us; speedup 1.0000x reference)
//
#include <hip/hip_runtime.h>
#include <math.h>

#define B_  32
#define TX_ 512
#define TY_ 2048
#define NF_ 80
#define NEGF (-1e9f)

typedef unsigned long long u64;
typedef const __attribute__((address_space(1))) void* gas_t;
typedef __attribute__((address_space(3))) void* las_t;
typedef float f32x4 __attribute__((ext_vector_type(4)));

static constexpr float LOG2PI_F = 1.8378770664093453f;
static constexpr float CONST_F = (float)(-0.5 * 1.8378770664093454966 * 80.0);

// ---------------- block reduce (sum), valid on thread 0 ----------------
__device__ inline float block_reduce_sum(float v) {
    __shared__ float sred[8];
    const int lane = threadIdx.x & 63, w = threadIdx.x >> 6;
    #pragma unroll
    for (int o = 32; o; o >>= 1) v += __shfl_down(v, o);
    if (lane == 0) sred[w] = v;
    __syncthreads();
    float r = 0.f;
    if (threadIdx.x == 0) {
        const int nw = blockDim.x >> 6;
        for (int k = 0; k < nw; ++k) r += sred[k];
    }
    return r;
}

// ---------------- ysq[b][j] = -0.5*sum_c y^2 ; musq[b][i] = -0.5*sum_c mu^2 ----
__global__ __launch_bounds__(256) void sq_kernel(
    const float* __restrict__ mu, const float* __restrict__ yy,
    float* __restrict__ musq, float* __restrict__ ysq)
{
    const int t = blockIdx.x * 256 + threadIdx.x;
    const int nY = B_ * TY_;
    if (t < nY) {
        const int b = t >> 11, j = t & (TY_ - 1);
        const float* p = yy + (size_t)b * NF_ * TY_ + j;
        float s = 0.f;
        #pragma unroll 8
        for (int k = 0; k < NF_; ++k) { float v = p[(size_t)k * TY_]; s = fmaf(v, v, s); }
        ysq[t] = -0.5f * s;
    } else {
        const int t2 = t - nY;
        if (t2 < B_ * TX_) {
            const int b = t2 >> 9, i = t2 & (TX_ - 1);
            const float* p = mu + (size_t)b * NF_ * TX_ + i;
            float s = 0.f;
            #pragma unroll 8
            for (int k = 0; k < NF_; ++k) { float v = p[(size_t)k * TX_]; s = fmaf(v, v, s); }
            musq[t2] = -0.5f * s;
        }
    }
}

// ---------------- lp[b][j][i] = masked log-prior (transposed layout) ----------
__global__ __launch_bounds__(256) void lp_kernel(
    const float* __restrict__ mu, const float* __restrict__ yy,
    const float* __restrict__ musq, const float* __restrict__ ysq,
    const int* __restrict__ xl, const int* __restrict__ yl,
    float* __restrict__ lp)
{
    __shared__ float smu[NF_][64];
    __shared__ float sy[NF_][64];
    const int b  = blockIdx.z;
    const int j0 = blockIdx.y * 64;
    const int ylen = yl[b];
    if (j0 >= ylen) return;                 // rows >= ylen are never read by DP
    const int i0 = blockIdx.x * 64;
    const int tid = threadIdx.x;

    const float* mub = mu + (size_t)b * NF_ * TX_ + i0;
    const float* yb  = yy + (size_t)b * NF_ * TY_ + j0;
    for (int t = tid; t < NF_ * 64; t += 256) {
        const int k = t >> 6, c = t & 63;
        smu[k][c] = mub[(size_t)k * TX_ + c];
        sy[k][c]  = yb[(size_t)k * TY_ + c];
    }
    __syncthreads();

    const int tx = tid & 15, ty = tid >> 4;
    float acc[4][4] = {};
    #pragma unroll 8
    for (int k = 0; k < NF_; ++k) {
        const float4 av = *(const float4*)&smu[k][tx * 4];
        const float4 bv = *(const float4*)&sy[k][ty * 4];
        const float a[4]  = {av.x, av.y, av.z, av.w};
        const float bb[4] = {bv.x, bv.y, bv.z, bv.w};
        #pragma unroll
        for (int r = 0; r < 4; ++r)
            #pragma unroll
            for (int c = 0; c < 4; ++c)
                acc[r][c] = fmaf(bb[r], a[c], acc[r][c]);
    }

    const int xlen = xl[b];
    float mq[4];
    #pragma unroll
    for (int c = 0; c < 4; ++c) mq[c] = musq[b * TX_ + i0 + tx * 4 + c];

    #pragma unroll
    for (int r = 0; r < 4; ++r) {
        const int j = j0 + ty * 4 + r;
        const float base = ysq[b * TY_ + j] + CONST_F;
        float4 o;
        float* po = &o.x;
        #pragma unroll
        for (int c = 0; c < 4; ++c) {
            const int i = i0 + tx * 4 + c;
            const float val = acc[r][c] + base + mq[c];
            po[c] = (i < xlen && j < ylen) ? val : NEGF;
        }
        *(float4*)&lp[((size_t)b * TY_ + j) * TX_ + i0 + tx * 4] = o;
    }
}

// ---------------- Viterbi DP + chunked backtrack, one wave per batch ----------
// LDS layout (dynamic, 162688 B total, <= 160 KiB):
//   dirs [2048][64] bytes  (1 bit per (row,col))             131072
//   ring [14][512] floats  (lp row staging, global_load_lds)  28672
//   durs [512] int                                             2048
//   stg  [112] u64  (backtrack window staging)                  896
// Critical-path design: per-row cross-lane via DPP wave_shr:1 (VALU, ~5cyc,
// replaces ds_bpermute ~120cyc); row data double-buffered in registers so the
// ds_read for row r+1 overlaps row r's VALU; staging via counted vmcnt (never
// drained in main loop). All in-loop LDS traffic is asm/builtin (round-5/6
// lesson: keeps the compiler's conservative LDS-DMA drains out of the loop).
__global__ __launch_bounds__(64) void dp_kernel(
    const float* __restrict__ lp, const int* __restrict__ xl, const int* __restrict__ yl,
    int* __restrict__ idx_out, int* __restrict__ dur_out)
{
    extern __shared__ unsigned char smem[];
    unsigned char* dirs = smem;
    float* ring = (float*)(smem + 131072);
    int*   durs = (int*)(smem + 131072 + 28672);
    u64*   stg  = (u64*)(smem + 131072 + 28672 + 2048);

    const int b = blockIdx.x;
    const int lane = threadIdx.x;
    const int xlen = xl[b], ylen = yl[b];
    const int last = ylen - 1;                 // DP rows 1..last (last >= 1023)

    // All C++ LDS writes happen BEFORE any LDS-DMA is issued.
    #pragma unroll
    for (int u = 0; u < TX_ / 64; ++u) durs[lane + u * 64] = 0;
    dirs[lane] = 0;                            // row j=0: no diagonal moves

    const float* lprow = lp + (size_t)b * TY_ * TX_;

    float v[8];
    #pragma unroll
    for (int u = 0; u < 8; ++u) v[u] = NEGF;
    if (lane == 0) v[0] = lprow[0];            // j=0: only i==0 valid
    // Force the load above to complete BEFORE any DMA is issued, so the
    // compiler doesn't park a vmcnt wait for it inside the main loop.
    asm volatile("" : "+v"(v[0]));

    const unsigned ring_base = (unsigned)(uintptr_t)(las_t)ring;
    const unsigned dirs_base = (unsigned)(uintptr_t)(las_t)dirs;

    // Stage one lp row (2048 B) into ring slot via 2x global_load_lds width-16.
    auto stage_row = [&](int row, int slot) {
        const float* src = lprow + (size_t)row * TX_ + lane * 4;
        float* dst = ring + slot * TX_;        // wave-uniform base
        __builtin_amdgcn_global_load_lds((gas_t)src,         (las_t)dst,         16, 0, 0);
        __builtin_amdgcn_global_load_lds((gas_t)(src + 256), (las_t)(dst + 256), 16, 0, 0);
    };

    // Issue (not wait) the two ds_read_b128 for a row into a register pair.
    auto ld_row = [&](int slot, f32x4& lo, f32x4& hi) {
        const unsigned laddr = ring_base + (unsigned)(slot * (TX_ * 4)) + (unsigned)(lane * 32);
        asm volatile("ds_read_b128 %0, %2\n\t"
                     "ds_read_b128 %1, %2 offset:16"
                     : "=&v"(lo), "=&v"(hi) : "v"(laddr));
    };

    // One DP row from registers. Cross-lane left-neighbor via DPP wave_shr:1
    // (lane l <- lane l-1; lane 0 garbage, masked to NEGF below).
    auto row_compute = [&](int j, const f32x4& lo, const f32x4& hi) {
        float left;
        asm volatile("s_nop 1\n\t"
                     "v_mov_b32_dpp %0, %1 wave_shr:1 row_mask:0xf bank_mask:0xf"
                     : "=&v"(left) : "v"(v[7]));
        if (lane == 0) left = NEGF;
        const float lv[8] = {lo.x, lo.y, lo.z, lo.w, hi.x, hi.y, hi.z, hi.w};
        unsigned bits = 0u;
        float nv[8];
        #pragma unroll
        for (int u2 = 7; u2 >= 1; --u2) {
            const float p = v[u2 - 1];
            if (p >= v[u2]) bits |= (1u << u2);
            nv[u2] = lv[u2] + fmaxf(v[u2], p);
        }
        if (left >= v[0]) bits |= 1u;
        nv[0] = lv[0] + fmaxf(v[0], left);
        #pragma unroll
        for (int u2 = 0; u2 < 8; ++u2) v[u2] = nv[u2];
        const unsigned daddr = dirs_base + (unsigned)(j * 64) + (unsigned)lane;
        asm volatile("ds_write_b8 %0, %1" :: "v"(daddr), "v"(bits));
    };

    // Uniform-shift renorm (wave-uniform, decision-invariant): keeps |v| small
    // so fp32 decisions track the reference.
    auto renorm = [&]() {
        const float m = __int_as_float(__builtin_amdgcn_readfirstlane(__float_as_int(v[0])));
        #pragma unroll
        for (int u = 0; u < 8; ++u) v[u] -= m;
    };

    // slot(j) = (j-1) % 14
    auto slotof = [&](int j) { int s = (j - 1) % 14; return s; };

    f32x4 Alo, Ahi, Blo, Bhi;

    // Prologue: stage rows 1..13 (26 loads out), retire row 1, read it into A.
    #pragma unroll
    for (int u = 0; u < 13; ++u) stage_row(1 + u, u);
    asm volatile("s_waitcnt vmcnt(24)" ::: "memory");
    ld_row(0, Alo, Ahi);
    asm volatile("s_waitcnt lgkmcnt(0)" ::: "memory");
    __builtin_amdgcn_sched_barrier(0);

    // Main loop, unroll-2 ping-pong. Invariant entering iter r: rows r+1..r+12
    // staged-not-retired (24 loads); row r's data in A.
    int r = 1, g = 0;
    while (r + 14 <= last) {
        stage_row(r + 13, slotof(r + 13));
        asm volatile("s_waitcnt vmcnt(24)" ::: "memory");
        ld_row(slotof(r + 1), Blo, Bhi);
        row_compute(r, Alo, Ahi);
        asm volatile("s_waitcnt lgkmcnt(0)" ::: "memory");
        __builtin_amdgcn_sched_barrier(0);

        stage_row(r + 14, slotof(r + 14));
        asm volatile("s_waitcnt vmcnt(24)" ::: "memory");
        ld_row(slotof(r + 2), Alo, Ahi);
        row_compute(r + 1, Blo, Bhi);
        asm volatile("s_waitcnt lgkmcnt(0)" ::: "memory");
        __builtin_amdgcn_sched_barrier(0);

        if (((++g) & 15) == 0) renorm();       // every 32 rows
        r += 2;
    }

    // Tail: rows r..last (13 or 14 rows). Stage the one possibly-missing row,
    // drain once, then finish from LDS with the same ping-pong.
    if (r + 13 <= last) stage_row(r + 13, slotof(r + 13));
    asm volatile("s_waitcnt vmcnt(0)" ::: "memory");
    while (r + 1 <= last) {
        ld_row(slotof(r + 1), Blo, Bhi);
        row_compute(r, Alo, Ahi);
        asm volatile("s_waitcnt lgkmcnt(0)" ::: "memory");
        __builtin_amdgcn_sched_barrier(0);
        if (r + 2 <= last) ld_row(slotof(r + 2), Alo, Ahi);
        row_compute(r + 1, Blo, Bhi);
        asm volatile("s_waitcnt lgkmcnt(0)" ::: "memory");
        __builtin_amdgcn_sched_barrier(0);
        r += 2;
    }
    if (r == last) row_compute(r, Alo, Ahi);

    asm volatile("s_waitcnt lgkmcnt(0)" ::: "memory");
    __builtin_amdgcn_sched_barrier(0);
    __syncthreads();

    // ---- backtrack: 56-row chunks, 128-col window staged to LDS, all lanes
    // redundantly chase the path with static-address loads ----
    int* iout = idx_out + b * TY_;
    for (int jj = ylen + lane; jj < TY_; jj += 64) iout[jj] = -1;

    int idx = xlen - 1;
    int cnt = 0;
    int j0 = last;
    while (j0 >= 0) {
        const int n = (j0 + 1 < 56) ? (j0 + 1) : 56;
        const int A = min(max((idx >> 6) - 1, 0), 6) * 64;  // window start
        if (lane < n) {
            const unsigned char* rp = &dirs[(j0 - lane) * 64 + (A >> 3)];
            stg[lane * 2]     = *(const u64*)rp;
            stg[lane * 2 + 1] = *(const u64*)(rp + 8);
        }
        __syncthreads();
        for (int u = 0; u < n; ++u) {             // uniform across lanes
            if (lane == 0) iout[j0 - u] = idx;
            const int sh = idx - A;
            const u64 w = (sh < 64) ? stg[u * 2] : stg[u * 2 + 1];
            const int bit = (int)((w >> (sh & 63)) & 1ULL);
            ++cnt;
            if (bit) { if (lane == 0) durs[idx] = cnt; cnt = 0; --idx; }
        }
        j0 -= n;
        __syncthreads();
    }
    if (lane == 0) durs[idx] = cnt;               // flush final run
    __syncthreads();

    #pragma unroll
    for (int u = 0; u < TX_ / 64; ++u)
        dur_out[b * TX_ + lane + u * 64] = durs[lane + u * 64];
}

// ---------------- scatter one-hot attention --------------------------------
__global__ __launch_bounds__(256) void attn_kernel(
    const int* __restrict__ idxs, float* __restrict__ attn /* out+2 */)
{
    const int i = blockIdx.x;   // TX
    const int b = blockIdx.y;
    const int t = threadIdx.x;  // 8 j's per thread
    const int4* ib = (const int4*)(idxs + b * TY_);
    float* ob = attn + ((size_t)b * TX_ + i) * TY_ + t * 8;
    const int4 q0 = ib[t * 2];
    const int4 q1 = ib[t * 2 + 1];
    ((float2*)ob)[0] = make_float2(q0.x == i ? 1.f : 0.f, q0.y == i ? 1.f : 0.f);
    ((float2*)ob)[1] = make_float2(q0.z == i ? 1.f : 0.f, q0.w == i ? 1.f : 0.f);
    ((float2*)ob)[2] = make_float2(q1.x == i ? 1.f : 0.f, q1.y == i ? 1.f : 0.f);
    ((float2*)ob)[3] = make_float2(q1.z == i ? 1.f : 0.f, q1.w == i ? 1.f : 0.f);
}

// ---------------- duration loss numerator ----------------------------------
__global__ __launch_bounds__(512) void dloss_kernel(
    const float* __restrict__ logw, const int* __restrict__ dur,
    const int* __restrict__ xl, double* __restrict__ acc)
{
    const int b = blockIdx.x;
    const int i = threadIdx.x;
    float s = 0.f;
    if (i < xl[b]) {
        const float lw  = logw[b * TX_ + i];
        const float lw_ = logf(1e-8f + (float)dur[b * TX_ + i]);
        const float d = lw - lw_;
        s = d * d;
    }
    const float r = block_reduce_sum(s);
    if (threadIdx.x == 0) atomicAdd(acc + 0, (double)r);
}

// ---------------- prior loss numerator -------------------------------------
__global__ __launch_bounds__(256) void ploss_kernel(
    const float* __restrict__ mu, const float* __restrict__ yy,
    const int* __restrict__ idxs, const int* __restrict__ yl,
    double* __restrict__ acc)
{
    const int b = blockIdx.y;
    const int j = blockIdx.x * 256 + threadIdx.x;
    float s = 0.f;
    if (j < yl[b]) {
        const int ii = idxs[b * TY_ + j];
        const float* yp = yy + (size_t)b * NF_ * TY_ + j;
        const float* mp = mu + (size_t)b * NF_ * TX_ + ii;
        float sq = 0.f;
        #pragma unroll 8
        for (int k = 0; k < NF_; ++k) {
            const float d = yp[(size_t)k * TY_] - mp[(size_t)k * TX_];
            sq = fmaf(d, d, sq);
        }
        s = 0.5f * (sq + (float)NF_ * LOG2PI_F);
    }
    const float r = block_reduce_sum(s);
    if (threadIdx.x == 0) atomicAdd(acc + 1, (double)r);
}

// ---------------- finalize: divide and write the two scalars ----------------
__global__ void fin_kernel(const double* __restrict__ acc,
                           const int* __restrict__ xl, const int* __restrict__ yl,
                           float* __restrict__ out)
{
    if (threadIdx.x == 0 && blockIdx.x == 0) {
        long long sx = 0, sy = 0;
        for (int b = 0; b < B_; ++b) { sx += xl[b]; sy += yl[b]; }
        out[0] = (float)(acc[0] / (double)sx);
        out[1] = (float)(acc[1] / ((double)sy * (double)NF_));
    }
}

extern "C" void kernel_launch(void* const* d_in, const int* in_sizes, int n_in,
                              void* d_out, int out_size, void* d_ws, size_t ws_size,
                              hipStream_t stream)
{
    const float* mu   = (const float*)d_in[0];
    const float* logw = (const float*)d_in[1];
    const float* yy   = (const float*)d_in[2];
    const int*   xl   = (const int*)d_in[3];
    const int*   yl   = (const int*)d_in[4];
    float* out = (float*)d_out;

    char* ws = (char*)d_ws;
    float*  ysq  = (float*)(ws);                      // B*TY f32   (256 KiB)
    float*  musq = (float*)(ws + 262144);             // B*TX f32   (64 KiB)
    int*    idxs = (int*)  (ws + 327680);             // B*TY i32   (256 KiB)
    int*    dur  = (int*)  (ws + 589824);             // B*TX i32   (64 KiB)
    double* acc  = (double*)(ws + 655360);            // 2 f64

    float* lpbuf = out;      // [B][TY][TX] scratch over the attn region
    float* attn  = out + 2;  // final [B][TX][TY] output (8B-aligned -> float2)

    const size_t dp_lds = 131072 + 28672 + 2048 + 896;   // 162688 B

    hipMemsetAsync(acc, 0, 16, stream);
    sq_kernel<<<dim3((B_ * (TY_ + TX_) + 255) / 256), 256, 0, stream>>>(mu, yy, musq, ysq);
    lp_kernel<<<dim3(TX_ / 64, TY_ / 64, B_), 256, 0, stream>>>(mu, yy, musq, ysq, xl, yl, lpbuf);
    dp_kernel<<<dim3(B_), 64, dp_lds, stream>>>(lpbuf, xl, yl, idxs, dur);
    attn_kernel<<<dim3(TX_, B_), 256, 0, stream>>>(idxs, attn);
    dloss_kernel<<<dim3(B_), 512, 0, stream>>>(logw, dur, xl, acc);
    ploss_kernel<<<dim3(TY_ / 256, B_), 256, 0, stream>>>(mu, yy, idxs, yl, acc);
    fin_kernel<<<1, 64, 0, stream>>>(acc, xl, yl, out);
}